// Round 3
// baseline (189.028 us; speedup 1.0000x reference)
//
#include <hip/hip_runtime.h>
#include <stdint.h>

#define NBATCH 8192
#define HID    128
#define DXC    64
#define NN     66
#define NSTEP  20
#define MROWS  16
#define RSTR   136   // rT LDS stride in bf16 elems (272 B rows: b128 reads spread 8x4-bank groups)
#define DSTR   280   // duL LDS stride in bf16 elems (560 B rows)

typedef __attribute__((ext_vector_type(8))) short short8;
typedef __attribute__((ext_vector_type(4))) float f32x4;

static __device__ __forceinline__ ushort f2bf(float f) {
  union { float f; uint32_t u; } v; v.f = f;
  uint32_t u = v.u;
  u += 0x7fffu + ((u >> 16) & 1u);
  return (ushort)(u >> 16);
}

// ---------------- Threefry2x32 (JAX exact) ----------------
__device__ __forceinline__ void tf2x32(uint32_t k1, uint32_t k2,
                                       uint32_t x0, uint32_t x1,
                                       uint32_t &o0, uint32_t &o1) {
  uint32_t k3 = k1 ^ k2 ^ 0x1BD11BDAu;
  x0 += k1; x1 += k2;
#define RND(r) do { x0 += x1; x1 = (x1 << (r)) | (x1 >> (32 - (r))); x1 ^= x0; } while (0)
  RND(13); RND(15); RND(26); RND(6);
  x0 += k2; x1 += k3 + 1u;
  RND(17); RND(29); RND(16); RND(24);
  x0 += k3; x1 += k1 + 2u;
  RND(13); RND(15); RND(26); RND(6);
  x0 += k1; x1 += k2 + 3u;
  RND(17); RND(29); RND(16); RND(24);
  x0 += k2; x1 += k3 + 4u;
  RND(13); RND(15); RND(26); RND(6);
  x0 += k3; x1 += k1 + 5u;
#undef RND
  o0 = x0; o1 = x1;
}

// ---------------- XLA ErfInv32 (Giles) ----------------
__device__ __forceinline__ float erfinv_f(float x) {
  float w = -log1pf(-x * x);
  float p1, p2;
  {
    float ww = w - 2.5f;
    float p = 2.81022636e-08f;
    p = fmaf(p, ww, 3.43273939e-07f);
    p = fmaf(p, ww, -3.5233877e-06f);
    p = fmaf(p, ww, -4.39150654e-06f);
    p = fmaf(p, ww, 0.00021858087f);
    p = fmaf(p, ww, -0.00125372503f);
    p = fmaf(p, ww, -0.00417768164f);
    p = fmaf(p, ww, 0.246640727f);
    p = fmaf(p, ww, 1.50140941f);
    p1 = p;
  }
  {
    float ww = sqrtf(w) - 3.0f;
    float p = -0.000200214257f;
    p = fmaf(p, ww, 0.000100950558f);
    p = fmaf(p, ww, 0.00134934322f);
    p = fmaf(p, ww, -0.00367342844f);
    p = fmaf(p, ww, 0.00573950773f);
    p = fmaf(p, ww, -0.0076224613f);
    p = fmaf(p, ww, 0.00943887047f);
    p = fmaf(p, ww, 1.00167406f);
    p = fmaf(p, ww, 2.83297682f);
    p2 = p;
  }
  float p = (w < 5.0f) ? p1 : p2;
  return p * x;
}

__device__ __forceinline__ float bits_to_normal(uint32_t bits) {
  float f = __uint_as_float((bits >> 9) | 0x3F800000u) - 1.0f;
  const float LO = -0.99999994f;
  float u = fmaxf(LO, fmaf(f, 2.0f, LO));
  return 1.41421356237f * erfinv_f(u);
}

// ---------------- single fused kernel: register-resident bf16 weights ----------------
__global__ __launch_bounds__(256, 2) void ebm_fused(
    const float* __restrict__ x, const float* __restrict__ t_in,
    const float* __restrict__ Bp,
    const float* __restrict__ W_in, const float* __restrict__ b_in,
    const float* __restrict__ WT1, const float* __restrict__ bT1,
    const float* __restrict__ WT2,
    const float* __restrict__ WY1, const float* __restrict__ bY1,
    const float* __restrict__ WY2,
    float* __restrict__ out) {

  __shared__ __align__(16) ushort rT[MROWS * RSTR];   // bf16 r, [m][k]
  __shared__ __align__(16) ushort duL[MROWS * DSTR];  // bf16 du, [m][T:0..127 | Y:128..255]
  __shared__ float xs[MROWS * DXC];
  __shared__ float zt[MROWS], zy[MROWS];
  __shared__ float gpart[4][MROWS][2];
  __shared__ uint32_t skeys[NSTEP][2];
  __shared__ float cb[NN];
  __shared__ float dsc[2];

  const int tid  = threadIdx.x;
  const int lane = tid & 63;
  const int wv   = tid >> 6;          // wave 0..3
  const int r16  = lane & 15;
  const int q    = lane >> 4;
  const int brow0 = blockIdx.x * MROWS;

  // ---- stage x tile, init z / step-keys ----
  ((float4*)xs)[tid] = ((const float4*)(x + (size_t)brow0 * DXC))[tid];
  if (tid < MROWS) { zt[tid] = t_in[brow0 + tid]; zy[tid] = 0.f; }
  if (tid < NSTEP) {
    uint32_t o0, o1;
    tf2x32(0u, 42u, 0u, (uint32_t)tid, o0, o1);
    skeys[tid][0] = o0; skeys[tid][1] = o1;
  }
  // ---- graph-conv collapse scalars d64,d65 (every block, once) ----
  if (tid < NN) {
    float rs = 0.f;
    for (int j = 0; j < NN; ++j) {
      if (j == tid) continue;
      if (tid == NN - 1 && j < DXC) continue;
      float v = Bp[tid * NN + j];
      rs += 1.f / (1.f + expf(-v));
    }
    cb[tid] = 1.f + rs / 66.f;
  }
  __syncthreads();
  if (tid < 2) {
    int i = 64 + tid;
    float s = 0.f;
    for (int j = 0; j < NN; ++j) {
      if (j == i) continue;
      if (i == NN - 1 && j < DXC) continue;
      float v = Bp[i * NN + j];
      s += (1.f / (1.f + expf(-v))) * cb[j];
    }
    dsc[tid] = cb[i] + s / 66.f;
  }
  __syncthreads();
  const float d64 = dsc[0], d65 = dsc[1];

  // per-wave output-column constants (coltiles c0=2wv, c1=2wv+1)
  const int n0 = 32 * wv + r16, n1 = n0 + 16;
  const float bT1a = bT1[n0], bT1b = bT1[n1];
  const float bY1a = bY1[n0], bY1b = bY1[n1];
  const ushort wT2a = f2bf(WT2[n0]), wT2b = f2bf(WT2[n1]);
  const ushort wY2a = f2bf(WY2[n0]), wY2b = f2bf(WY2[n1]);
  const float wtA = W_in[64 * HID + n0], wtB = W_in[64 * HID + n1];
  const float wyA = W_in[65 * HID + n0], wyB = W_in[65 * HID + n1];
  const float2 wtk2 = ((const float2*)(W_in + 64 * HID))[lane];
  const float2 wyk2 = ((const float2*)(W_in + 65 * HID))[lane];

  // ---- bake step-invariant bf16 MFMA B-fragments into registers ----
  // fwd: frag[kt][j] = d * W[kt*32+q*8+j][n]     (B-layout for u = r @ Wd)
  // bwd: frag[kt][j] = d * W[n][kt*32+q*8+j]     (B-layout for v = du @ Wd^T)
  short8 fT0[4], fT1[4], fY0[4], fY1[4];
  short8 hT0[4], hT1[4], hY0[4], hY1[4];
#pragma unroll
  for (int kt = 0; kt < 4; ++kt) {
    const int kb = kt * 32 + q * 8;
    short8 a0, a1, b0, b1;
#pragma unroll
    for (int j = 0; j < 8; ++j) {
      a0[j] = (short)f2bf(d64 * WT1[(kb + j) * HID + n0]);
      a1[j] = (short)f2bf(d64 * WT1[(kb + j) * HID + n1]);
      b0[j] = (short)f2bf(d65 * WY1[(kb + j) * HID + n0]);
      b1[j] = (short)f2bf(d65 * WY1[(kb + j) * HID + n1]);
    }
    fT0[kt] = a0; fT1[kt] = a1; fY0[kt] = b0; fY1[kt] = b1;
    const float* pT0 = WT1 + (size_t)n0 * HID + kb;
    const float* pT1 = WT1 + (size_t)n1 * HID + kb;
    const float* pY0 = WY1 + (size_t)n0 * HID + kb;
    const float* pY1 = WY1 + (size_t)n1 * HID + kb;
    short8 c0v, c1v, e0, e1;
#pragma unroll
    for (int j = 0; j < 8; ++j) {
      c0v[j] = (short)f2bf(d64 * pT0[j]);
      c1v[j] = (short)f2bf(d64 * pT1[j]);
      e0[j]  = (short)f2bf(d65 * pY0[j]);
      e1[j]  = (short)f2bf(d65 * pY1[j]);
    }
    hT0[kt] = c0v; hT1[kt] = c1v; hY0[kt] = e0; hY1[kt] = e1;
  }

  // ---- static part of h0 for my 4 rows x 2 cols ----
  float h0x_[4][2];
  {
    float2 b2 = ((const float2*)b_in)[lane];
#pragma unroll
    for (int m = 0; m < 4; ++m) { h0x_[m][0] = b2.x; h0x_[m][1] = b2.y; }
    for (int cc = 0; cc < DXC; ++cc) {
      float2 w2 = ((const float2*)(W_in + cc * HID))[lane];
#pragma unroll
      for (int m = 0; m < 4; ++m) {
        float xv = xs[(wv * 4 + m) * DXC + cc];
        h0x_[m][0] = fmaf(xv, w2.x, h0x_[m][0]);
        h0x_[m][1] = fmaf(xv, w2.y, h0x_[m][1]);
      }
    }
  }
  __syncthreads();

  for (int s = 0; s < NSTEP; ++s) {
    // ---- A: r = relu(h0x + t*wt + y*wy), bf16 into rT (packed b32 writes) ----
#pragma unroll
    for (int m = 0; m < 4; ++m) {
      int mg = wv * 4 + m;
      float ztv = zt[mg], zyv = zy[mg];
      float h0 = fmaf(zyv, wyk2.x, fmaf(ztv, wtk2.x, h0x_[m][0]));
      float h1 = fmaf(zyv, wyk2.y, fmaf(ztv, wtk2.y, h0x_[m][1]));
      ushort lo = f2bf(fmaxf(h0, 0.f));
      ushort hi = f2bf(fmaxf(h1, 0.f));
      ((uint32_t*)rT)[mg * (RSTR / 2) + lane] = (uint32_t)lo | ((uint32_t)hi << 16);
    }
    __syncthreads();

    // ---- F: forward u = d*(r@W) + b -> du masks into duL ----
    {
      short8 ar[4];
#pragma unroll
      for (int kt = 0; kt < 4; ++kt)
        ar[kt] = *reinterpret_cast<const short8*>(&rT[r16 * RSTR + kt * 32 + q * 8]);

      f32x4 aT0 = {0.f, 0.f, 0.f, 0.f}, aT1 = aT0, aY0 = aT0, aY1 = aT0;
#pragma unroll
      for (int kt = 0; kt < 4; ++kt) {
        aT0 = __builtin_amdgcn_mfma_f32_16x16x32_bf16(ar[kt], fT0[kt], aT0, 0, 0, 0);
        aT1 = __builtin_amdgcn_mfma_f32_16x16x32_bf16(ar[kt], fT1[kt], aT1, 0, 0, 0);
        aY0 = __builtin_amdgcn_mfma_f32_16x16x32_bf16(ar[kt], fY0[kt], aY0, 0, 0, 0);
        aY1 = __builtin_amdgcn_mfma_f32_16x16x32_bf16(ar[kt], fY1[kt], aY1, 0, 0, 0);
      }
#pragma unroll
      for (int reg = 0; reg < 4; ++reg) {
        int row = q * 4 + reg;
        duL[row * DSTR + n0]       = (aT0[reg] + bT1a > 0.f) ? wT2a : (ushort)0;
        duL[row * DSTR + n1]       = (aT1[reg] + bT1b > 0.f) ? wT2b : (ushort)0;
        duL[row * DSTR + 128 + n0] = (aY0[reg] + bY1a > 0.f) ? wY2a : (ushort)0;
        duL[row * DSTR + 128 + n1] = (aY1[reg] + bY1b > 0.f) ? wY2b : (ushort)0;
      }
    }
    __syncthreads();

    // ---- B: backward v = du_T@(d64*WT1^T) + du_Y@(d65*WY1^T); mask; dots ----
    {
      short8 d8[4];
#pragma unroll
      for (int kt = 0; kt < 4; ++kt)
        d8[kt] = *reinterpret_cast<const short8*>(&duL[r16 * DSTR + kt * 32 + q * 8]);
      f32x4 g0 = {0.f, 0.f, 0.f, 0.f}, g1 = g0;
#pragma unroll
      for (int kt = 0; kt < 4; ++kt) {
        g0 = __builtin_amdgcn_mfma_f32_16x16x32_bf16(d8[kt], hT0[kt], g0, 0, 0, 0);
        g1 = __builtin_amdgcn_mfma_f32_16x16x32_bf16(d8[kt], hT1[kt], g1, 0, 0, 0);
      }
#pragma unroll
      for (int kt = 0; kt < 4; ++kt)
        d8[kt] = *reinterpret_cast<const short8*>(&duL[r16 * DSTR + 128 + kt * 32 + q * 8]);
#pragma unroll
      for (int kt = 0; kt < 4; ++kt) {
        g0 = __builtin_amdgcn_mfma_f32_16x16x32_bf16(d8[kt], hY0[kt], g0, 0, 0, 0);
        g1 = __builtin_amdgcn_mfma_f32_16x16x32_bf16(d8[kt], hY1[kt], g1, 0, 0, 0);
      }
      float pt[4], py[4];
#pragma unroll
      for (int reg = 0; reg < 4; ++reg) {
        int row = q * 4 + reg;
        short rv0 = (short)rT[row * RSTR + n0];
        short rv1 = (short)rT[row * RSTR + n1];
        float v0 = (rv0 > 0) ? g0[reg] : 0.f;
        float v1 = (rv1 > 0) ? g1[reg] : 0.f;
        pt[reg] = fmaf(v0, wtA, v1 * wtB);
        py[reg] = fmaf(v0, wyA, v1 * wyB);
      }
#pragma unroll
      for (int reg = 0; reg < 4; ++reg) {
#pragma unroll
        for (int off = 1; off < 16; off <<= 1) {
          pt[reg] += __shfl_xor(pt[reg], off);
          py[reg] += __shfl_xor(py[reg], off);
        }
      }
      if (r16 == 0) {
#pragma unroll
        for (int reg = 0; reg < 4; ++reg) {
          gpart[wv][q * 4 + reg][0] = pt[reg];
          gpart[wv][q * 4 + reg][1] = py[reg];
        }
      }
    }
    __syncthreads();

    // ---- D: z update with exact JAX noise ----
    if (tid < MROWS) {
      float gt = gpart[0][tid][0] + gpart[1][tid][0] + gpart[2][tid][0] + gpart[3][tid][0];
      float gy = gpart[0][tid][1] + gpart[1][tid][1] + gpart[2][tid][1] + gpart[3][tid][1];
      uint32_t idx = (uint32_t)(2 * (brow0 + tid));
      uint32_t o0, o1;
      tf2x32(skeys[s][0], skeys[s][1], 0u, idx, o0, o1);
      float nt = bits_to_normal(o0 ^ o1);
      tf2x32(skeys[s][0], skeys[s][1], 0u, idx + 1u, o0, o1);
      float ny = bits_to_normal(o0 ^ o1);
      zt[tid] = (zt[tid] - 0.005f * gt) + 0.1f * nt;
      zy[tid] = (zy[tid] - 0.005f * gy) + 0.1f * ny;
    }
    __syncthreads();
  }

  if (tid < MROWS) out[brow0 + tid] = zy[tid];
}

extern "C" void kernel_launch(void* const* d_in, const int* in_sizes, int n_in,
                              void* d_out, int out_size, void* d_ws, size_t ws_size,
                              hipStream_t stream) {
  const float* x    = (const float*)d_in[0];
  const float* t_in = (const float*)d_in[1];
  const float* Bp   = (const float*)d_in[2];
  const float* W_in = (const float*)d_in[3];
  const float* b_in = (const float*)d_in[4];
  const float* WT1  = (const float*)d_in[5];
  const float* bT1  = (const float*)d_in[6];
  const float* WT2  = (const float*)d_in[7];
  const float* WY1  = (const float*)d_in[9];
  const float* bY1  = (const float*)d_in[10];
  const float* WY2  = (const float*)d_in[11];
  float* out = (float*)d_out;

  ebm_fused<<<NBATCH / MROWS, 256, 0, stream>>>(
      x, t_in, Bp, W_in, b_in, WT1, bT1, WT2, WY1, bY1, WY2, out);
}

// Round 4
// 181.303 us; speedup vs baseline: 1.0426x; 1.0426x over previous
//
#include <hip/hip_runtime.h>
#include <stdint.h>

#define NBATCH 8192
#define HID    128
#define DXC    64
#define NN     66
#define NSTEP  20
#define MROWS  16
#define RSTR   136   // rT LDS stride in bf16 elems
#define DSTR   280   // duL LDS stride in bf16 elems

typedef __attribute__((ext_vector_type(8))) short short8;
typedef __attribute__((ext_vector_type(4))) float f32x4;

static __device__ __forceinline__ ushort f2bf(float f) {
  union { float f; uint32_t u; } v; v.f = f;
  uint32_t u = v.u;
  u += 0x7fffu + ((u >> 16) & 1u);
  return (ushort)(u >> 16);
}

// ---------------- Threefry2x32 (JAX exact) ----------------
__device__ __forceinline__ void tf2x32(uint32_t k1, uint32_t k2,
                                       uint32_t x0, uint32_t x1,
                                       uint32_t &o0, uint32_t &o1) {
  uint32_t k3 = k1 ^ k2 ^ 0x1BD11BDAu;
  x0 += k1; x1 += k2;
#define RND(r) do { x0 += x1; x1 = (x1 << (r)) | (x1 >> (32 - (r))); x1 ^= x0; } while (0)
  RND(13); RND(15); RND(26); RND(6);
  x0 += k2; x1 += k3 + 1u;
  RND(17); RND(29); RND(16); RND(24);
  x0 += k3; x1 += k1 + 2u;
  RND(13); RND(15); RND(26); RND(6);
  x0 += k1; x1 += k2 + 3u;
  RND(17); RND(29); RND(16); RND(24);
  x0 += k2; x1 += k3 + 4u;
  RND(13); RND(15); RND(26); RND(6);
  x0 += k3; x1 += k1 + 5u;
#undef RND
  o0 = x0; o1 = x1;
}

// ---------------- XLA ErfInv32 (Giles) ----------------
__device__ __forceinline__ float erfinv_f(float x) {
  float w = -log1pf(-x * x);
  float p1, p2;
  {
    float ww = w - 2.5f;
    float p = 2.81022636e-08f;
    p = fmaf(p, ww, 3.43273939e-07f);
    p = fmaf(p, ww, -3.5233877e-06f);
    p = fmaf(p, ww, -4.39150654e-06f);
    p = fmaf(p, ww, 0.00021858087f);
    p = fmaf(p, ww, -0.00125372503f);
    p = fmaf(p, ww, -0.00417768164f);
    p = fmaf(p, ww, 0.246640727f);
    p = fmaf(p, ww, 1.50140941f);
    p1 = p;
  }
  {
    float ww = sqrtf(w) - 3.0f;
    float p = -0.000200214257f;
    p = fmaf(p, ww, 0.000100950558f);
    p = fmaf(p, ww, 0.00134934322f);
    p = fmaf(p, ww, -0.00367342844f);
    p = fmaf(p, ww, 0.00573950773f);
    p = fmaf(p, ww, -0.0076224613f);
    p = fmaf(p, ww, 0.00943887047f);
    p = fmaf(p, ww, 1.00167406f);
    p = fmaf(p, ww, 2.83297682f);
    p2 = p;
  }
  float p = (w < 5.0f) ? p1 : p2;
  return p * x;
}

__device__ __forceinline__ float bits_to_normal(uint32_t bits) {
  float f = __uint_as_float((bits >> 9) | 0x3F800000u) - 1.0f;
  const float LO = -0.99999994f;
  float u = fmaxf(LO, fmaf(f, 2.0f, LO));
  return 1.41421356237f * erfinv_f(u);
}

// bwd fragment index: [t(2)][coltile c(8)][kt(4)][lane(64)] -> short8 slot
#define FRAG_SLOT(t, c, kt, lane) (((((t) * 8 + (c)) * 4 + (kt)) * 64 + (lane)))

// ---------------- fused kernel: fwd weights in VGPR, bwd weights in LDS ----------------
__global__ __launch_bounds__(256) void ebm_fused(
    const float* __restrict__ x, const float* __restrict__ t_in,
    const float* __restrict__ Bp,
    const float* __restrict__ W_in, const float* __restrict__ b_in,
    const float* __restrict__ WT1, const float* __restrict__ bT1,
    const float* __restrict__ WT2,
    const float* __restrict__ WY1, const float* __restrict__ bY1,
    const float* __restrict__ WY2,
    float* __restrict__ out) {

  // 64 KiB bwd-fragment store; xs (4 KiB, prologue-only) aliases its head.
  __shared__ __align__(16) ushort fragL[2 * 8 * 4 * 64 * 8];
  __shared__ __align__(16) ushort rT[MROWS * RSTR];
  __shared__ __align__(16) ushort duL[MROWS * DSTR];
  __shared__ float zt[MROWS], zy[MROWS];
  __shared__ float gpart[4][MROWS][2];
  __shared__ uint32_t skeys[NSTEP][2];
  __shared__ float cb[NN];
  __shared__ float dsc[2];

  float* xs = reinterpret_cast<float*>(fragL);   // alias, dead before frag bake

  const int tid  = threadIdx.x;
  const int lane = tid & 63;
  const int wv   = tid >> 6;          // wave 0..3
  const int r16  = lane & 15;
  const int q    = lane >> 4;
  const int brow0 = blockIdx.x * MROWS;

  // ---- stage x tile, init z / step-keys / sigmoid row sums ----
  ((float4*)xs)[tid] = ((const float4*)(x + (size_t)brow0 * DXC))[tid];
  if (tid < MROWS) { zt[tid] = t_in[brow0 + tid]; zy[tid] = 0.f; }
  if (tid < NSTEP) {
    uint32_t o0, o1;
    tf2x32(0u, 42u, 0u, (uint32_t)tid, o0, o1);
    skeys[tid][0] = o0; skeys[tid][1] = o1;
  }
  if (tid < NN) {
    float rs = 0.f;
    for (int j = 0; j < NN; ++j) {
      if (j == tid) continue;
      if (tid == NN - 1 && j < DXC) continue;
      float v = Bp[tid * NN + j];
      rs += 1.f / (1.f + expf(-v));
    }
    cb[tid] = 1.f + rs / 66.f;
  }
  __syncthreads();
  if (tid < 2) {
    int i = 64 + tid;
    float s = 0.f;
    for (int j = 0; j < NN; ++j) {
      if (j == i) continue;
      if (i == NN - 1 && j < DXC) continue;
      float v = Bp[i * NN + j];
      s += (1.f / (1.f + expf(-v))) * cb[j];
    }
    dsc[tid] = cb[i] + s / 66.f;
  }
  __syncthreads();
  const float d64 = dsc[0], d65 = dsc[1];

  // per-wave output-column constants (coltiles c0=2wv, c1=2wv+1)
  const int n0 = 32 * wv + r16, n1 = n0 + 16;
  const float bT1a = bT1[n0], bT1b = bT1[n1];
  const float bY1a = bY1[n0], bY1b = bY1[n1];
  const ushort wT2a = f2bf(WT2[n0]), wT2b = f2bf(WT2[n1]);
  const ushort wY2a = f2bf(WY2[n0]), wY2b = f2bf(WY2[n1]);
  const float wtA = W_in[64 * HID + n0], wtB = W_in[64 * HID + n1];
  const float wyA = W_in[65 * HID + n0], wyB = W_in[65 * HID + n1];
  const float2 wtk2 = ((const float2*)(W_in + 64 * HID))[lane];
  const float2 wyk2 = ((const float2*)(W_in + 65 * HID))[lane];

  // ---- static part of h0 for my 4 rows x 2 cols (consumes xs) ----
  float h0x_[4][2];
  {
    float2 b2 = ((const float2*)b_in)[lane];
#pragma unroll
    for (int m = 0; m < 4; ++m) { h0x_[m][0] = b2.x; h0x_[m][1] = b2.y; }
    for (int cc = 0; cc < DXC; ++cc) {
      float2 w2 = ((const float2*)(W_in + cc * HID))[lane];
#pragma unroll
      for (int m = 0; m < 4; ++m) {
        float xv = xs[(wv * 4 + m) * DXC + cc];
        h0x_[m][0] = fmaf(xv, w2.x, h0x_[m][0]);
        h0x_[m][1] = fmaf(xv, w2.y, h0x_[m][1]);
      }
    }
  }
  __syncthreads();   // xs dead from here; fragL region reusable

  // ---- bake fwd bf16 B-fragments into registers (64 VGPRs) ----
  // fwd: frag[kt][j] = d * W[kt*32+q*8+j][n]
  short8 fT0[4], fT1[4], fY0[4], fY1[4];
#pragma unroll
  for (int kt = 0; kt < 4; ++kt) {
    const int kb = kt * 32 + q * 8;
    short8 a0, a1, b0, b1;
#pragma unroll
    for (int j = 0; j < 8; ++j) {
      a0[j] = (short)f2bf(d64 * WT1[(kb + j) * HID + n0]);
      a1[j] = (short)f2bf(d64 * WT1[(kb + j) * HID + n1]);
      b0[j] = (short)f2bf(d65 * WY1[(kb + j) * HID + n0]);
      b1[j] = (short)f2bf(d65 * WY1[(kb + j) * HID + n1]);
    }
    fT0[kt] = a0; fT1[kt] = a1; fY0[kt] = b0; fY1[kt] = b1;
  }

  // ---- bake bwd fragments into LDS, fragment-ordered (conflict-free reads) ----
  // element(t, c, kt, lane, j) = d * W[16c + (lane&15)][kt*32 + (lane>>4)*8 + j]
#pragma unroll
  for (int t = 0; t < 2; ++t) {
    const float* W = t ? WY1 : WT1;
    const float d = t ? d65 : d64;
#pragma unroll
    for (int ci = 0; ci < 2; ++ci) {
      const int c = 2 * wv + ci;
      const int krow = 16 * c + r16;
#pragma unroll
      for (int kt = 0; kt < 4; ++kt) {
        const int kb = kt * 32 + q * 8;
        const float* p = W + (size_t)krow * HID + kb;
        ushort v[8];
#pragma unroll
        for (int j = 0; j < 8; ++j) v[j] = f2bf(d * p[j]);
        uint4 st;
        st.x = (uint32_t)v[0] | ((uint32_t)v[1] << 16);
        st.y = (uint32_t)v[2] | ((uint32_t)v[3] << 16);
        st.z = (uint32_t)v[4] | ((uint32_t)v[5] << 16);
        st.w = (uint32_t)v[6] | ((uint32_t)v[7] << 16);
        ((uint4*)fragL)[FRAG_SLOT(t, c, kt, lane)] = st;
      }
    }
  }
  __syncthreads();

  for (int s = 0; s < NSTEP; ++s) {
    // ---- A: r = relu(h0x + t*wt + y*wy), bf16 into rT ----
#pragma unroll
    for (int m = 0; m < 4; ++m) {
      int mg = wv * 4 + m;
      float ztv = zt[mg], zyv = zy[mg];
      float h0 = fmaf(zyv, wyk2.x, fmaf(ztv, wtk2.x, h0x_[m][0]));
      float h1 = fmaf(zyv, wyk2.y, fmaf(ztv, wtk2.y, h0x_[m][1]));
      ushort lo = f2bf(fmaxf(h0, 0.f));
      ushort hi = f2bf(fmaxf(h1, 0.f));
      ((uint32_t*)rT)[mg * (RSTR / 2) + lane] = (uint32_t)lo | ((uint32_t)hi << 16);
    }
    __syncthreads();

    // ---- F: forward u = d*(r@W) + b -> du masks into duL ----
    {
      short8 ar[4];
#pragma unroll
      for (int kt = 0; kt < 4; ++kt)
        ar[kt] = *reinterpret_cast<const short8*>(&rT[r16 * RSTR + kt * 32 + q * 8]);

      f32x4 aT0 = {0.f, 0.f, 0.f, 0.f}, aT1 = aT0, aY0 = aT0, aY1 = aT0;
#pragma unroll
      for (int kt = 0; kt < 4; ++kt) {
        aT0 = __builtin_amdgcn_mfma_f32_16x16x32_bf16(ar[kt], fT0[kt], aT0, 0, 0, 0);
        aT1 = __builtin_amdgcn_mfma_f32_16x16x32_bf16(ar[kt], fT1[kt], aT1, 0, 0, 0);
        aY0 = __builtin_amdgcn_mfma_f32_16x16x32_bf16(ar[kt], fY0[kt], aY0, 0, 0, 0);
        aY1 = __builtin_amdgcn_mfma_f32_16x16x32_bf16(ar[kt], fY1[kt], aY1, 0, 0, 0);
      }
#pragma unroll
      for (int reg = 0; reg < 4; ++reg) {
        int row = q * 4 + reg;
        duL[row * DSTR + n0]       = (aT0[reg] + bT1a > 0.f) ? wT2a : (ushort)0;
        duL[row * DSTR + n1]       = (aT1[reg] + bT1b > 0.f) ? wT2b : (ushort)0;
        duL[row * DSTR + 128 + n0] = (aY0[reg] + bY1a > 0.f) ? wY2a : (ushort)0;
        duL[row * DSTR + 128 + n1] = (aY1[reg] + bY1b > 0.f) ? wY2b : (ushort)0;
      }
    }
    __syncthreads();

    // ---- B: backward v = du_T@(d64*WT1^T) + du_Y@(d65*WY1^T); mask; dots ----
    {
      short8 d8[4];
#pragma unroll
      for (int kt = 0; kt < 4; ++kt)
        d8[kt] = *reinterpret_cast<const short8*>(&duL[r16 * DSTR + kt * 32 + q * 8]);
      f32x4 g0 = {0.f, 0.f, 0.f, 0.f}, g1 = g0;
#pragma unroll
      for (int kt = 0; kt < 4; ++kt) {
        short8 w0 = *reinterpret_cast<const short8*>(&fragL[FRAG_SLOT(0, 2 * wv, kt, lane) * 8]);
        short8 w1 = *reinterpret_cast<const short8*>(&fragL[FRAG_SLOT(0, 2 * wv + 1, kt, lane) * 8]);
        g0 = __builtin_amdgcn_mfma_f32_16x16x32_bf16(d8[kt], w0, g0, 0, 0, 0);
        g1 = __builtin_amdgcn_mfma_f32_16x16x32_bf16(d8[kt], w1, g1, 0, 0, 0);
      }
#pragma unroll
      for (int kt = 0; kt < 4; ++kt)
        d8[kt] = *reinterpret_cast<const short8*>(&duL[r16 * DSTR + 128 + kt * 32 + q * 8]);
#pragma unroll
      for (int kt = 0; kt < 4; ++kt) {
        short8 w0 = *reinterpret_cast<const short8*>(&fragL[FRAG_SLOT(1, 2 * wv, kt, lane) * 8]);
        short8 w1 = *reinterpret_cast<const short8*>(&fragL[FRAG_SLOT(1, 2 * wv + 1, kt, lane) * 8]);
        g0 = __builtin_amdgcn_mfma_f32_16x16x32_bf16(d8[kt], w0, g0, 0, 0, 0);
        g1 = __builtin_amdgcn_mfma_f32_16x16x32_bf16(d8[kt], w1, g1, 0, 0, 0);
      }
      float pt[4], py[4];
#pragma unroll
      for (int reg = 0; reg < 4; ++reg) {
        int row = q * 4 + reg;
        short rv0 = (short)rT[row * RSTR + n0];
        short rv1 = (short)rT[row * RSTR + n1];
        float v0 = (rv0 > 0) ? g0[reg] : 0.f;
        float v1 = (rv1 > 0) ? g1[reg] : 0.f;
        pt[reg] = fmaf(v0, wtA, v1 * wtB);
        py[reg] = fmaf(v0, wyA, v1 * wyB);
      }
#pragma unroll
      for (int reg = 0; reg < 4; ++reg) {
#pragma unroll
        for (int off = 1; off < 16; off <<= 1) {
          pt[reg] += __shfl_xor(pt[reg], off);
          py[reg] += __shfl_xor(py[reg], off);
        }
      }
      if (r16 == 0) {
#pragma unroll
        for (int reg = 0; reg < 4; ++reg) {
          gpart[wv][q * 4 + reg][0] = pt[reg];
          gpart[wv][q * 4 + reg][1] = py[reg];
        }
      }
    }
    __syncthreads();

    // ---- D: z update with exact JAX noise ----
    if (tid < MROWS) {
      float gt = gpart[0][tid][0] + gpart[1][tid][0] + gpart[2][tid][0] + gpart[3][tid][0];
      float gy = gpart[0][tid][1] + gpart[1][tid][1] + gpart[2][tid][1] + gpart[3][tid][1];
      uint32_t idx = (uint32_t)(2 * (brow0 + tid));
      uint32_t o0, o1;
      tf2x32(skeys[s][0], skeys[s][1], 0u, idx, o0, o1);
      float nt = bits_to_normal(o0 ^ o1);
      tf2x32(skeys[s][0], skeys[s][1], 0u, idx + 1u, o0, o1);
      float ny = bits_to_normal(o0 ^ o1);
      zt[tid] = (zt[tid] - 0.005f * gt) + 0.1f * nt;
      zy[tid] = (zy[tid] - 0.005f * gy) + 0.1f * ny;
    }
    __syncthreads();
  }

  if (tid < MROWS) out[brow0 + tid] = zy[tid];
}

extern "C" void kernel_launch(void* const* d_in, const int* in_sizes, int n_in,
                              void* d_out, int out_size, void* d_ws, size_t ws_size,
                              hipStream_t stream) {
  const float* x    = (const float*)d_in[0];
  const float* t_in = (const float*)d_in[1];
  const float* Bp   = (const float*)d_in[2];
  const float* W_in = (const float*)d_in[3];
  const float* b_in = (const float*)d_in[4];
  const float* WT1  = (const float*)d_in[5];
  const float* bT1  = (const float*)d_in[6];
  const float* WT2  = (const float*)d_in[7];
  const float* WY1  = (const float*)d_in[9];
  const float* bY1  = (const float*)d_in[10];
  const float* WY2  = (const float*)d_in[11];
  float* out = (float*)d_out;

  ebm_fused<<<NBATCH / MROWS, 256, 0, stream>>>(
      x, t_in, Bp, W_in, b_in, WT1, bT1, WT2, WY1, bY1, WY2, out);
}